// Round 6
// baseline (115.718 us; speedup 1.0000x reference)
//
#include <hip/hip_runtime.h>
#include <hip/hip_bf16.h>

#define EMBED 1024
#define HEADS 16
#define HDIM  64
#define BATCH 4
#define SEQ   1024

typedef __attribute__((ext_vector_type(8))) short  short8;
typedef __attribute__((ext_vector_type(4))) short  short4v;
typedef __attribute__((ext_vector_type(4))) float  float4v;

// 16x16x16 bf16 MFMA (A/B = 2 VGPRs, C/D = 4; ISA: v_mfma_f32_16x16x16_bf16).
// Builtin when the device pass has it; inline-asm fallback otherwise.  The
// host pass parses the asm branch but never codegens it.
static __device__ __forceinline__ float4v mfma16(short4v a, short4v b, float4v c) {
#if defined(__HIP_DEVICE_COMPILE__) && __has_builtin(__builtin_amdgcn_mfma_f32_16x16x16bf16_1k)
  return __builtin_amdgcn_mfma_f32_16x16x16bf16_1k(a, b, c, 0, 0, 0);
#else
  float4v d;
  asm("v_mfma_f32_16x16x16_bf16 %0, %1, %2, %3"
      : "=v"(d)
      : "v"(a), "v"(b), "v"(c));
  return d;
#endif
}

// f32 -> bf16 (RNE)
static __device__ __forceinline__ short f2b(float f) {
  unsigned u = __builtin_bit_cast(unsigned, f);
  unsigned r = (u + 0x7FFFu + ((u >> 16) & 1u)) >> 16;
  return (short)(unsigned short)r;
}

// pack two f32 -> bf16x2 (RNE) in one dword (lo = a, hi = b)
static __device__ __forceinline__ unsigned pkbf(float a, float b) {
  float2 t; t.x = a; t.y = b;
  __hip_bfloat162 h = __float22bfloat162_rn(t);
  unsigned u; __builtin_memcpy(&u, &h, 4);
  return u;
}

static __device__ __forceinline__ short8 cvt8(const float* p) {
  float4v a = *(const float4v*)p;
  float4v b = *(const float4v*)(p + 4);
  short8 r;
  r[0]=f2b(a[0]); r[1]=f2b(a[1]); r[2]=f2b(a[2]); r[3]=f2b(a[3]);
  r[4]=f2b(b[0]); r[5]=f2b(b[1]); r[6]=f2b(b[2]); r[7]=f2b(b[3]);
  return r;
}

#define QSCL 0.04508422002778011f  // log2(e) / sqrt(EMBED)

// ---------------------------------------------------------------------------
// Kernel 1 (fused preprocessing): proj (blocks 0..3071, 4 waves each doing an
// independent (16-row, head, tensor) tile), maskbits (3072..19455),
// wcvt (19456..20479).  Independent work co-resident -> BW/latency overlap.
// ---------------------------------------------------------------------------
__global__ __launch_bounds__(256) void k_pre(
    const float* __restrict__ values, const float* __restrict__ keys,
    const float* __restrict__ query,
    const float* __restrict__ Wv, const float* __restrict__ Wq,
    const float* __restrict__ Wk, const float* __restrict__ Wu,
    const int* __restrict__ mask,
    short* __restrict__ qp, short* __restrict__ kp, short* __restrict__ vpT,
    unsigned* __restrict__ mbits, short* __restrict__ wub) {
  const int b = blockIdx.x;
  if (b < 3072) {
    // ---- projections: wave W = b*4 + w handles (r0, h, z)
    const int W = b * 4 + (threadIdx.x >> 6);
    const int z = W >> 12;            // 0=q,1=k,2=v
    const int rem = W & 4095;
    const int h = rem & 15;
    const int r0 = (rem >> 4) * 16;
    const float* in_; const float* Wm;
    if (z == 0)      { in_ = query;  Wm = Wq; }
    else if (z == 1) { in_ = keys;   Wm = Wk; }
    else             { in_ = values; Wm = Wv; }
    const int l = threadIdx.x & 63, lr = l & 15, g = l >> 4;
    const int n = r0 >> 10, s0 = r0 & 1023;
    const int nh = n * HEADS + h;

    float4v acc[4];
    for (int nt = 0; nt < 4; ++nt) acc[nt] = (float4v){0.f, 0.f, 0.f, 0.f};
    for (int kb = 0; kb < 2; ++kb) {
      short8 af = cvt8(in_ + (size_t)(r0 + lr) * EMBED + h * HDIM + kb * 32 + g * 8);
      for (int nt = 0; nt < 4; ++nt) {
        short8 bf = cvt8(Wm + (size_t)(nt * 16 + lr) * HDIM + kb * 32 + g * 8);
        acc[nt] = __builtin_amdgcn_mfma_f32_16x16x32_bf16(af, bf, acc[nt], 0, 0, 0);
      }
    }
    if (z == 2) {
      for (int nt = 0; nt < 4; ++nt) {
        short4v r;
        r[0]=f2b(acc[nt][0]); r[1]=f2b(acc[nt][1]);
        r[2]=f2b(acc[nt][2]); r[3]=f2b(acc[nt][3]);
        *(short4v*)(vpT + (size_t)(nh * HDIM + nt * 16 + lr) * SEQ + s0 + g * 4) = r;
      }
    } else {
      short* outp = (z == 0) ? qp : kp;
      const float scl = (z == 0) ? QSCL : 1.0f;
      for (int nt = 0; nt < 4; ++nt)
        for (int i = 0; i < 4; ++i)
          outp[(size_t)(nh * SEQ + s0 + g * 4 + i) * HDIM + nt * 16 + lr] =
              f2b(acc[nt][i] * scl);
    }
  } else if (b < 3072 + 16384) {
    // ---- mask -> bitmask
    int tid = (b - 3072) * 256 + threadIdx.x;
    int v = mask[tid];
    unsigned long long bal = __ballot(v != 0);
    int l = threadIdx.x & 63;
    if ((l & 31) == 0) mbits[tid >> 5] = (unsigned)(bal >> (l & 32));
  } else {
    // ---- Wu -> bf16
    int i4 = ((b - 19456) * 256 + threadIdx.x) * 4;
    float4v v = *(const float4v*)(Wu + i4);
    short4v r; r[0]=f2b(v[0]); r[1]=f2b(v[1]); r[2]=f2b(v[2]); r[3]=f2b(v[3]);
    *(short4v*)(wub + i4) = r;
  }
}

// ---------------------------------------------------------------------------
// Kernel 2: flash attention, 4-wave blocks (QBLK=64), LDS K/V double-buffered,
// reg-staged (T14).  16B-block XOR swizzle; all frag-read addresses collapse
// to 6 VGPRs (row&7 == lr&7) + literal ds offsets via #pragma unroll 2.
// PV uses 16x16x16 MFMA whose B operand is the packed P dwords in-register
// (zero P transpose / zero P LDS).  XCD-swizzled flat grid: each XCD owns
// 8 whole (n,h) groups -> K/V stay in its L2.
// ---------------------------------------------------------------------------
__global__ __launch_bounds__(256, 5) void k_attn(
    const short* __restrict__ qp, const short* __restrict__ kp,
    const short* __restrict__ vpT, const unsigned* __restrict__ mbits,
    short* __restrict__ ao) {
  // XCD-aware decode of flat 1024-block grid (bijective)
  const int bid = blockIdx.x;
  const int work = (bid & 7) * 128 + (bid >> 3);
  const int qt = work & 15, grp = work >> 4;
  const int h = grp & 15, n = grp >> 4;

  const int t256 = threadIdx.x;
  const int w = t256 >> 6, l = t256 & 63, lr = l & 15, g = l >> 4;
  const int nh = n * HEADS + h;
  const int q0 = qt * 64 + w * 16;
  const short* qb  = qp  + (size_t)nh * SEQ * HDIM;
  const short* kbp = kp  + (size_t)nh * SEQ * HDIM;
  const short* vb  = vpT + (size_t)nh * HDIM * SEQ;
  const unsigned* mrow = mbits + (size_t)(n * SEQ + q0 + lr) * 32;

  __shared__ __align__(16) short kls[2][4096];   // K tile [64 key][64 d], swizzled
  __shared__ __align__(16) short vls[2][4096];   // V^T tile [64 d][64 key], swizzled

  // staging slots: thread stages 16B at slots t256, t256+256
  const int s0 = t256, s1 = t256 + 256;
  const int r0s = s0 >> 3, c0s = s0 & 7, r1s = s1 >> 3, c1s = s1 & 7;
  const int ld0 = r0s * 64 + ((c0s ^ (r0s & 7)) << 3);
  const int ld1 = r1s * 64 + ((c1s ^ (r1s & 7)) << 3);

  // frag-read bases (shorts); row&7 == lr&7 for every frag row
  const int e = lr & 7;
  const int kbase0 = lr * 64 + ((g ^ e) << 3);
  const int kbase1 = lr * 64 + (((4 + g) ^ e) << 3);
  int va4[4];
#pragma unroll
  for (int a = 0; a < 4; ++a)
    va4[a] = lr * 64 + ((((2 * a) + (g >> 1)) ^ e) << 3) + (g & 1) * 4;

  // ---- prologue: stage tile 0
  {
    short8 k0 = *(const short8*)(kbp + s0 * 8);
    short8 k1 = *(const short8*)(kbp + s1 * 8);
    short8 v0 = *(const short8*)(vb + (size_t)r0s * SEQ + c0s * 8);
    short8 v1 = *(const short8*)(vb + (size_t)r1s * SEQ + c1s * 8);
    *(short8*)(&kls[0][0] + ld0) = k0;
    *(short8*)(&kls[0][0] + ld1) = k1;
    *(short8*)(&vls[0][0] + ld0) = v0;
    *(short8*)(&vls[0][0] + ld1) = v1;
  }

  // Q fragments (B-operand): lane holds Q[q=lr][d=g*8+j]
  const short8 qf0 = *(const short8*)(qb + (q0 + lr) * HDIM + g * 8);
  const short8 qf1 = *(const short8*)(qb + (q0 + lr) * HDIM + 32 + g * 8);

  float4v accd[4];
#pragma unroll
  for (int dt = 0; dt < 4; ++dt) accd[dt] = (float4v){0.f, 0.f, 0.f, 0.f};
  float m_i = -3.0e18f, l_i = 0.f;   // per-lane (row q=lr), log2 domain

  __syncthreads();

#pragma unroll 2
  for (int t = 0; t < 16; ++t) {
    const int cur = t & 1, nxt = cur ^ 1;
    const int kt = t * 64;
    // ---- issue prefetch of tile t+1 (global -> regs), hidden under compute
    short8 stK0, stK1, stV0, stV1;
    if (t < 15) {
      const int kn = kt + 64;
      stK0 = *(const short8*)(kbp + kn * 64 + s0 * 8);
      stK1 = *(const short8*)(kbp + kn * 64 + s1 * 8);
      stV0 = *(const short8*)(vb + (size_t)r0s * SEQ + kn + c0s * 8);
      stV1 = *(const short8*)(vb + (size_t)r1s * SEQ + kn + c1s * 8);
    }
    // ---- S^T = K·Q^T : sT[a][i] = S^T[key=a*16+g*4+i][q=lr]
    float4v sT[4];
#pragma unroll
    for (int a = 0; a < 4; ++a) {
      short8 kf0 = *(const short8*)(&kls[cur][a * 1024] + kbase0);
      short8 kf1 = *(const short8*)(&kls[cur][a * 1024] + kbase1);
      float4v z = (float4v){0.f, 0.f, 0.f, 0.f};
      z = __builtin_amdgcn_mfma_f32_16x16x32_bf16(kf0, qf0, z, 0, 0, 0);
      sT[a] = __builtin_amdgcn_mfma_f32_16x16x32_bf16(kf1, qf1, z, 0, 0, 0);
    }
    // ---- local max over 16 logits (balanced tree; masked included: exact)
    float ma = fmaxf(fmaxf(sT[0][0], sT[0][1]), fmaxf(sT[0][2], sT[0][3]));
    float mb = fmaxf(fmaxf(sT[1][0], sT[1][1]), fmaxf(sT[1][2], sT[1][3]));
    float mc = fmaxf(fmaxf(sT[2][0], sT[2][1]), fmaxf(sT[2][2], sT[2][3]));
    float md = fmaxf(fmaxf(sT[3][0], sT[3][1]), fmaxf(sT[3][2], sT[3][3]));
    float lm = fmaxf(fmaxf(ma, mb), fmaxf(mc, md));
    // ---- defer-max: rescale only when some row's max grew past THR=8
    if (__any(lm > m_i + 8.0f)) {
      float tm = lm;
      tm = fmaxf(tm, __shfl_xor(tm, 16, 64));
      tm = fmaxf(tm, __shfl_xor(tm, 32, 64));
      float mn = fmaxf(m_i, tm);
      float sc = exp2f(m_i - mn);
      m_i = mn;
      l_i *= sc;
#pragma unroll
      for (int dt = 0; dt < 4; ++dt)
#pragma unroll
        for (int i = 0; i < 4; ++i) accd[dt][i] *= sc;
    }
    // ---- mask words for row q0+lr, keys kt..kt+63
    uint2 mw = *(const uint2*)(mrow + 2 * t);
    const unsigned t0m = mw.x >> (g * 4);
    const unsigned t1m = mw.y >> (g * 4);
    // ---- p = exp2(s-m) * bit, packed bf16x2 pairs (PV B-frags, in-register)
    short4v pb[4];
    float psum = 0.f;
#pragma unroll
    for (int a = 0; a < 4; ++a) {
      unsigned ta = ((a & 2) ? t1m : t0m) >> ((a & 1) * 16);
      float p0 = exp2f(sT[a][0] - m_i); p0 = (ta & 1u) ? p0 : 0.f;
      float p1 = exp2f(sT[a][1] - m_i); p1 = (ta & 2u) ? p1 : 0.f;
      float p2 = exp2f(sT[a][2] - m_i); p2 = (ta & 4u) ? p2 : 0.f;
      float p3 = exp2f(sT[a][3] - m_i); p3 = (ta & 8u) ? p3 : 0.f;
      psum += (p0 + p1) + (p2 + p3);
      uint2 u; u.x = pkbf(p0, p1); u.y = pkbf(p2, p3);
      __builtin_memcpy(&pb[a], &u, 8);
    }
    l_i += psum;
    // ---- O^T += V^T · P^T via 16x16x16 MFMA (B = pb[a], no LDS roundtrip)
#pragma unroll
    for (int dt = 0; dt < 4; ++dt) {
#pragma unroll
      for (int a = 0; a < 4; ++a) {
        short4v vf = *(const short4v*)(&vls[cur][dt * 1024] + va4[a]);
        accd[dt] = mfma16(vf, pb[a], accd[dt]);
      }
    }
    // ---- publish prefetched tile, barrier
    if (t < 15) {
      *(short8*)(&kls[nxt][0] + ld0) = stK0;
      *(short8*)(&kls[nxt][0] + ld1) = stK1;
      *(short8*)(&vls[nxt][0] + ld0) = stV0;
      *(short8*)(&vls[nxt][0] + ld1) = stV1;
      __syncthreads();
    }
  }
  // ---- epilogue
  l_i += __shfl_xor(l_i, 16, 64);
  l_i += __shfl_xor(l_i, 32, 64);
  float inv = 1.f / fmaxf(l_i, 1e-35f);
  short* aorow = ao + (size_t)(n * SEQ + q0 + lr) * EMBED + h * HDIM;
#pragma unroll
  for (int dt = 0; dt < 4; ++dt) {
    short4v r;
    r[0] = f2b(accd[dt][0] * inv);
    r[1] = f2b(accd[dt][1] * inv);
    r[2] = f2b(accd[dt][2] * inv);
    r[3] = f2b(accd[dt][3] * inv);
    *(short4v*)(aorow + dt * 16 + g * 4) = r;
  }
}

// ---------------------------------------------------------------------------
// Kernel 3: out = ao @ Wu^T + bu.  64x64 tile, 4 waves, LDS-staged bf16 tiles
// with stride-40 (bf16) padding.
// ---------------------------------------------------------------------------
__global__ __launch_bounds__(256) void k_gemm(
    const short* __restrict__ ao, const short* __restrict__ wub,
    const float* __restrict__ bu, float* __restrict__ out) {
  const int r0 = blockIdx.x * 64, c0 = blockIdx.y * 64;
  const int t = threadIdx.x;
  const int w = t >> 6, l = t & 63, lr = l & 15, g = l >> 4;
  __shared__ __align__(16) short albuf[64 * 40];
  __shared__ __align__(16) short blbuf[64 * 40];
  float4v acc[4];
  for (int nt = 0; nt < 4; ++nt) acc[nt] = (float4v){0.f, 0.f, 0.f, 0.f};
  const int lrow = t >> 2, lcb = (t & 3) * 8;
  for (int kbk = 0; kbk < EMBED; kbk += 32) {
    __syncthreads();
    *(short8*)(albuf + lrow * 40 + lcb) =
        *(const short8*)(ao + (size_t)(r0 + lrow) * EMBED + kbk + lcb);
    *(short8*)(blbuf + lrow * 40 + lcb) =
        *(const short8*)(wub + (size_t)(c0 + lrow) * EMBED + kbk + lcb);
    __syncthreads();
    short8 af = *(const short8*)(albuf + (16 * w + lr) * 40 + g * 8);
    for (int nt = 0; nt < 4; ++nt) {
      short8 bf = *(const short8*)(blbuf + (nt * 16 + lr) * 40 + g * 8);
      acc[nt] = __builtin_amdgcn_mfma_f32_16x16x32_bf16(af, bf, acc[nt], 0, 0, 0);
    }
  }
  for (int nt = 0; nt < 4; ++nt)
    for (int i = 0; i < 4; ++i) {
      int row = r0 + 16 * w + g * 4 + i;
      int col = c0 + nt * 16 + lr;
      out[(size_t)row * EMBED + col] = acc[nt][i] + bu[col];
    }
}

// ---------------------------------------------------------------------------
extern "C" void kernel_launch(void* const* d_in, const int* in_sizes, int n_in,
                              void* d_out, int out_size, void* d_ws, size_t ws_size,
                              hipStream_t stream) {
  const float* values = (const float*)d_in[0];
  const float* keys   = (const float*)d_in[1];
  const float* query  = (const float*)d_in[2];
  const int*   mask   = (const int*)d_in[3];
  const float* Wv     = (const float*)d_in[4];
  const float* Wq     = (const float*)d_in[5];
  const float* Wk     = (const float*)d_in[6];
  const float* Wu     = (const float*)d_in[7];
  const float* bu     = (const float*)d_in[8];
  float* out = (float*)d_out;

  char* ws = (char*)d_ws;
  short* qp  = (short*)ws;                        // 8 MB  (4M bf16)
  short* kp  = qp + (1u << 22);                   // 8 MB
  short* vpT = kp + (1u << 22);                   // 8 MB (transposed V)
  short* ao  = vpT + (1u << 22);                  // 8 MB
  unsigned* mbits = (unsigned*)(ws + (32u << 20));        // 512 KB
  short* wub = (short*)(ws + (32u << 20) + (512u << 10)); // 2 MB

  k_pre<<<dim3(20480), 256, 0, stream>>>(values, keys, query, Wv, Wq, Wk, Wu,
                                         mask, qp, kp, vpT, mbits, wub);
  k_attn<<<dim3(1024), 256, 0, stream>>>(qp, kp, vpT, mbits, ao);
  k_gemm<<<dim3(64, 16), 256, 0, stream>>>(ao, wub, bu, out);
}

// Round 7
// 102.560 us; speedup vs baseline: 1.1283x; 1.1283x over previous
//
#include <hip/hip_runtime.h>
#include <hip/hip_bf16.h>

#define EMBED 1024
#define HEADS 16
#define HDIM  64
#define BATCH 4
#define SEQ   1024

typedef __attribute__((ext_vector_type(8))) short  short8;
typedef __attribute__((ext_vector_type(4))) short  short4v;
typedef __attribute__((ext_vector_type(4))) float  float4v;

// 16x16x16 bf16 MFMA (A/B = 2 VGPRs, C/D = 4; ISA: v_mfma_f32_16x16x16_bf16).
static __device__ __forceinline__ float4v mfma16(short4v a, short4v b, float4v c) {
#if defined(__HIP_DEVICE_COMPILE__) && __has_builtin(__builtin_amdgcn_mfma_f32_16x16x16bf16_1k)
  return __builtin_amdgcn_mfma_f32_16x16x16bf16_1k(a, b, c, 0, 0, 0);
#else
  float4v d;
  asm("v_mfma_f32_16x16x16_bf16 %0, %1, %2, %3"
      : "=v"(d)
      : "v"(a), "v"(b), "v"(c));
  return d;
#endif
}

// f32 -> bf16 (RNE)
static __device__ __forceinline__ short f2b(float f) {
  unsigned u = __builtin_bit_cast(unsigned, f);
  unsigned r = (u + 0x7FFFu + ((u >> 16) & 1u)) >> 16;
  return (short)(unsigned short)r;
}

// pack two f32 -> bf16x2 (RNE) in one dword (lo = a, hi = b)
static __device__ __forceinline__ unsigned pkbf(float a, float b) {
  float2 t; t.x = a; t.y = b;
  __hip_bfloat162 h = __float22bfloat162_rn(t);
  unsigned u; __builtin_memcpy(&u, &h, 4);
  return u;
}

static __device__ __forceinline__ short8 cvt8(const float* p) {
  float4v a = *(const float4v*)p;
  float4v b = *(const float4v*)(p + 4);
  short8 r;
  r[0]=f2b(a[0]); r[1]=f2b(a[1]); r[2]=f2b(a[2]); r[3]=f2b(a[3]);
  r[4]=f2b(b[0]); r[5]=f2b(b[1]); r[6]=f2b(b[2]); r[7]=f2b(b[3]);
  return r;
}

#define QSCL 0.04508422002778011f  // log2(e) / sqrt(EMBED)

// ---------------------------------------------------------------------------
// Kernel 1 (fused preprocessing): proj (blocks 0..3071), maskbits
// (3072..19455), wcvt (19456..20479).
// vpT is stored with keys PERMUTED within each 64-key tile:
//   pos(k) = ((k>>5)&1)*32 + ((k>>2)&3)*8 + ((k>>4)&1)*4 + (k&3)
// so one b128 LDS read in attn yields the A-frags of two 16x16x16 PV MFMAs.
// ---------------------------------------------------------------------------
__global__ __launch_bounds__(256) void k_pre(
    const float* __restrict__ values, const float* __restrict__ keys,
    const float* __restrict__ query,
    const float* __restrict__ Wv, const float* __restrict__ Wq,
    const float* __restrict__ Wk, const float* __restrict__ Wu,
    const int* __restrict__ mask,
    short* __restrict__ qp, short* __restrict__ kp, short* __restrict__ vpT,
    unsigned* __restrict__ mbits, short* __restrict__ wub) {
  const int b = blockIdx.x;
  if (b < 3072) {
    const int W = b * 4 + (threadIdx.x >> 6);
    const int z = W >> 12;            // 0=q,1=k,2=v
    const int rem = W & 4095;
    const int h = rem & 15;
    const int r0 = (rem >> 4) * 16;
    const float* in_; const float* Wm;
    if (z == 0)      { in_ = query;  Wm = Wq; }
    else if (z == 1) { in_ = keys;   Wm = Wk; }
    else             { in_ = values; Wm = Wv; }
    const int l = threadIdx.x & 63, lr = l & 15, g = l >> 4;
    const int n = r0 >> 10, s0 = r0 & 1023;
    const int nh = n * HEADS + h;

    float4v acc[4];
    for (int nt = 0; nt < 4; ++nt) acc[nt] = (float4v){0.f, 0.f, 0.f, 0.f};
    for (int kb = 0; kb < 2; ++kb) {
      short8 af = cvt8(in_ + (size_t)(r0 + lr) * EMBED + h * HDIM + kb * 32 + g * 8);
      for (int nt = 0; nt < 4; ++nt) {
        short8 bf = cvt8(Wm + (size_t)(nt * 16 + lr) * HDIM + kb * 32 + g * 8);
        acc[nt] = __builtin_amdgcn_mfma_f32_16x16x32_bf16(af, bf, acc[nt], 0, 0, 0);
      }
    }
    if (z == 2) {
      // permuted-key transposed V store
      const int s = s0 + g * 4;          // 4-aligned key block start
      const int kk = s & 63;
      const int pos = ((kk >> 5) & 1) * 32 + ((kk >> 2) & 3) * 8 + ((kk >> 4) & 1) * 4;
      for (int nt = 0; nt < 4; ++nt) {
        short4v r;
        r[0]=f2b(acc[nt][0]); r[1]=f2b(acc[nt][1]);
        r[2]=f2b(acc[nt][2]); r[3]=f2b(acc[nt][3]);
        *(short4v*)(vpT + (size_t)(nh * HDIM + nt * 16 + lr) * SEQ + (s & ~63) + pos) = r;
      }
    } else {
      short* outp = (z == 0) ? qp : kp;
      const float scl = (z == 0) ? QSCL : 1.0f;
      for (int nt = 0; nt < 4; ++nt)
        for (int i = 0; i < 4; ++i)
          outp[(size_t)(nh * SEQ + s0 + g * 4 + i) * HDIM + nt * 16 + lr] =
              f2b(acc[nt][i] * scl);
    }
  } else if (b < 3072 + 16384) {
    int tid = (b - 3072) * 256 + threadIdx.x;
    int v = mask[tid];
    unsigned long long bal = __ballot(v != 0);
    int l = threadIdx.x & 63;
    if ((l & 31) == 0) mbits[tid >> 5] = (unsigned)(bal >> (l & 32));
  } else {
    int i4 = ((b - 19456) * 256 + threadIdx.x) * 4;
    float4v v = *(const float4v*)(Wu + i4);
    short4v r; r[0]=f2b(v[0]); r[1]=f2b(v[1]); r[2]=f2b(v[2]); r[3]=f2b(v[3]);
    *(short4v*)(wub + i4) = r;
  }
}

// ---------------------------------------------------------------------------
// Kernel 2: flash attention, 4-wave blocks (QBLK=64), LDS K/V double-buffered,
// reg-staged (T14), 16B-block XOR swizzle.  PV: in-register P (16x16x16 MFMA);
// V-frags come from ONE b128 read per (dt,h2) thanks to the vpT key
// permutation -> same conflict-free pattern as the K reads.  XCD-swizzled
// flat grid keeps each (n,h)'s K/V in one XCD's L2.
// ---------------------------------------------------------------------------
__global__ __launch_bounds__(256, 5) void k_attn(
    const short* __restrict__ qp, const short* __restrict__ kp,
    const short* __restrict__ vpT, const unsigned* __restrict__ mbits,
    short* __restrict__ ao) {
  const int bid = blockIdx.x;
  const int work = (bid & 7) * 128 + (bid >> 3);
  const int qt = work & 15, grp = work >> 4;
  const int h = grp & 15, n = grp >> 4;

  const int t256 = threadIdx.x;
  const int w = t256 >> 6, l = t256 & 63, lr = l & 15, g = l >> 4;
  const int nh = n * HEADS + h;
  const int q0 = qt * 64 + w * 16;
  const short* qb  = qp  + (size_t)nh * SEQ * HDIM;
  const short* kbp = kp  + (size_t)nh * SEQ * HDIM;
  const short* vb  = vpT + (size_t)nh * HDIM * SEQ;
  const unsigned* mrow = mbits + (size_t)(n * SEQ + q0 + lr) * 32;

  __shared__ __align__(16) short kls[2][4096];   // K tile [64 key][64 d], swizzled
  __shared__ __align__(16) short vls[2][4096];   // V^T tile [64 d][64 pos], swizzled

  const int s0 = t256, s1 = t256 + 256;
  const int r0s = s0 >> 3, c0s = s0 & 7, r1s = s1 >> 3, c1s = s1 & 7;
  const int ld0 = r0s * 64 + ((c0s ^ (r0s & 7)) << 3);
  const int ld1 = r1s * 64 + ((c1s ^ (r1s & 7)) << 3);

  // frag-read bases; row&7 == lr&7 for every frag row
  const int e = lr & 15 & 7;
  const int base0 = lr * 64 + ((g ^ e) << 3);        // blocks 0..3 side
  const int base1 = lr * 64 + (((4 + g) ^ e) << 3);  // blocks 4..7 side

  // ---- prologue: stage tile 0
  {
    short8 k0 = *(const short8*)(kbp + s0 * 8);
    short8 k1 = *(const short8*)(kbp + s1 * 8);
    short8 v0 = *(const short8*)(vb + (size_t)r0s * SEQ + c0s * 8);
    short8 v1 = *(const short8*)(vb + (size_t)r1s * SEQ + c1s * 8);
    *(short8*)(&kls[0][0] + ld0) = k0;
    *(short8*)(&kls[0][0] + ld1) = k1;
    *(short8*)(&vls[0][0] + ld0) = v0;
    *(short8*)(&vls[0][0] + ld1) = v1;
  }

  const short8 qf0 = *(const short8*)(qb + (q0 + lr) * HDIM + g * 8);
  const short8 qf1 = *(const short8*)(qb + (q0 + lr) * HDIM + 32 + g * 8);

  float4v accd[4];
#pragma unroll
  for (int dt = 0; dt < 4; ++dt) accd[dt] = (float4v){0.f, 0.f, 0.f, 0.f};
  float m_i = -3.0e18f, l_i = 0.f;   // per-lane (row q=lr), log2 domain

  __syncthreads();

#pragma unroll 2
  for (int t = 0; t < 16; ++t) {
    const int cur = t & 1, nxt = cur ^ 1;
    const int kt = t * 64;
    // ---- prefetch tile t+1 (global -> regs), hidden under compute
    short8 stK0, stK1, stV0, stV1;
    if (t < 15) {
      const int kn = kt + 64;
      stK0 = *(const short8*)(kbp + kn * 64 + s0 * 8);
      stK1 = *(const short8*)(kbp + kn * 64 + s1 * 8);
      stV0 = *(const short8*)(vb + (size_t)r0s * SEQ + kn + c0s * 8);
      stV1 = *(const short8*)(vb + (size_t)r1s * SEQ + kn + c1s * 8);
    }
    // ---- S^T = K·Q^T : sT[a][i] = S^T[key=a*16+g*4+i][q=lr]
    float4v sT[4];
#pragma unroll
    for (int a = 0; a < 4; ++a) {
      short8 kf0 = *(const short8*)(&kls[cur][a * 1024] + base0);
      short8 kf1 = *(const short8*)(&kls[cur][a * 1024] + base1);
      float4v z = (float4v){0.f, 0.f, 0.f, 0.f};
      z = __builtin_amdgcn_mfma_f32_16x16x32_bf16(kf0, qf0, z, 0, 0, 0);
      sT[a] = __builtin_amdgcn_mfma_f32_16x16x32_bf16(kf1, qf1, z, 0, 0, 0);
    }
    // ---- local max over 16 logits (masked included: exact)
    float ma = fmaxf(fmaxf(sT[0][0], sT[0][1]), fmaxf(sT[0][2], sT[0][3]));
    float mb = fmaxf(fmaxf(sT[1][0], sT[1][1]), fmaxf(sT[1][2], sT[1][3]));
    float mc = fmaxf(fmaxf(sT[2][0], sT[2][1]), fmaxf(sT[2][2], sT[2][3]));
    float md = fmaxf(fmaxf(sT[3][0], sT[3][1]), fmaxf(sT[3][2], sT[3][3]));
    float lm = fmaxf(fmaxf(ma, mb), fmaxf(mc, md));
    // ---- defer-max: rescale only when some row's max grew past THR=8
    if (__any(lm > m_i + 8.0f)) {
      float tm = lm;
      tm = fmaxf(tm, __shfl_xor(tm, 16, 64));
      tm = fmaxf(tm, __shfl_xor(tm, 32, 64));
      float mn = fmaxf(m_i, tm);
      float sc = exp2f(m_i - mn);
      m_i = mn;
      l_i *= sc;
#pragma unroll
      for (int dt = 0; dt < 4; ++dt)
#pragma unroll
        for (int i = 0; i < 4; ++i) accd[dt][i] *= sc;
    }
    // ---- mask words for row q0+lr, keys kt..kt+63
    uint2 mw = *(const uint2*)(mrow + 2 * t);
    const unsigned t0m = mw.x >> (g * 4);
    const unsigned t1m = mw.y >> (g * 4);
    // ---- p = exp2(s-m) * bit, packed bf16x2 pairs (PV B-frags, in-register)
    short4v pb[4];
    float psum = 0.f;
#pragma unroll
    for (int a = 0; a < 4; ++a) {
      unsigned ta = ((a & 2) ? t1m : t0m) >> ((a & 1) * 16);
      float p0 = exp2f(sT[a][0] - m_i); p0 = (ta & 1u) ? p0 : 0.f;
      float p1 = exp2f(sT[a][1] - m_i); p1 = (ta & 2u) ? p1 : 0.f;
      float p2 = exp2f(sT[a][2] - m_i); p2 = (ta & 4u) ? p2 : 0.f;
      float p3 = exp2f(sT[a][3] - m_i); p3 = (ta & 8u) ? p3 : 0.f;
      psum += (p0 + p1) + (p2 + p3);
      uint2 u; u.x = pkbf(p0, p1); u.y = pkbf(p2, p3);
      __builtin_memcpy(&pb[a], &u, 8);
    }
    l_i += psum;
    // ---- O^T += V^T · P^T : one b128 V read feeds two 16x16x16 MFMAs
#pragma unroll
    for (int dt = 0; dt < 4; ++dt) {
#pragma unroll
      for (int h2 = 0; h2 < 2; ++h2) {
        short8 vf = *(const short8*)(&vls[cur][dt * 1024] + (h2 ? base1 : base0));
        short4v lo = __builtin_shufflevector(vf, vf, 0, 1, 2, 3);
        short4v hi = __builtin_shufflevector(vf, vf, 4, 5, 6, 7);
        accd[dt] = mfma16(lo, pb[2 * h2], accd[dt]);
        accd[dt] = mfma16(hi, pb[2 * h2 + 1], accd[dt]);
      }
    }
    // ---- publish prefetched tile, barrier
    if (t < 15) {
      *(short8*)(&kls[nxt][0] + ld0) = stK0;
      *(short8*)(&kls[nxt][0] + ld1) = stK1;
      *(short8*)(&vls[nxt][0] + ld0) = stV0;
      *(short8*)(&vls[nxt][0] + ld1) = stV1;
      __syncthreads();
    }
  }
  // ---- epilogue
  l_i += __shfl_xor(l_i, 16, 64);
  l_i += __shfl_xor(l_i, 32, 64);
  float inv = 1.f / fmaxf(l_i, 1e-35f);
  short* aorow = ao + (size_t)(n * SEQ + q0 + lr) * EMBED + h * HDIM;
#pragma unroll
  for (int dt = 0; dt < 4; ++dt) {
    short4v r;
    r[0] = f2b(accd[dt][0] * inv);
    r[1] = f2b(accd[dt][1] * inv);
    r[2] = f2b(accd[dt][2] * inv);
    r[3] = f2b(accd[dt][3] * inv);
    *(short4v*)(aorow + dt * 16 + g * 4) = r;
  }
}

// ---------------------------------------------------------------------------
// Kernel 3: out = ao @ Wu^T + bu.  128x128 tile, 8 waves (each 64x32),
// BK=64, double-buffered reg-staged LDS with 16B-block XOR swizzle.
// Grid 32x8 = 256 blocks = 1/CU.
// ---------------------------------------------------------------------------
__global__ __launch_bounds__(512, 1) void k_gemm(
    const short* __restrict__ ao, const short* __restrict__ wub,
    const float* __restrict__ bu, float* __restrict__ out) {
  const int r0 = blockIdx.x * 128, c0 = blockIdx.y * 128;
  const int t = threadIdx.x;
  const int w = t >> 6, l = t & 63, lr = l & 15, g = l >> 4;
  const int wr = w >> 2, wc = w & 3;   // wave tile: rows wr*64.., cols wc*32..

  __shared__ __align__(16) short als[2][128 * 64];
  __shared__ __align__(16) short bls[2][128 * 64];

  // staging: 1024 16B-chunks per tile; thread handles chunks t and t+512
  const int ar0 = t >> 3, ac0 = t & 7;
  const int ar1 = (t + 512) >> 3, ac1 = (t + 512) & 7;
  const int ld0 = ar0 * 64 + ((ac0 ^ (ar0 & 7)) << 3);
  const int ld1 = ar1 * 64 + ((ac1 ^ (ar1 & 7)) << 3);
  const short* agp0 = ao  + (size_t)(r0 + ar0) * EMBED + ac0 * 8;
  const short* agp1 = ao  + (size_t)(r0 + ar1) * EMBED + ac1 * 8;
  const short* bgp0 = wub + (size_t)(c0 + ar0) * EMBED + ac0 * 8;
  const short* bgp1 = wub + (size_t)(c0 + ar1) * EMBED + ac1 * 8;

  // frag-read offsets (compile-time-indexed arrays via full unroll)
  int aoff[4][2], boff[2][2];
#pragma unroll
  for (int fr = 0; fr < 4; ++fr) {
    const int ra = wr * 64 + fr * 16 + lr;
#pragma unroll
    for (int kk = 0; kk < 2; ++kk)
      aoff[fr][kk] = ra * 64 + (((kk * 4 + g) ^ (ra & 7)) << 3);
  }
#pragma unroll
  for (int fc = 0; fc < 2; ++fc) {
    const int rb = wc * 32 + fc * 16 + lr;
#pragma unroll
    for (int kk = 0; kk < 2; ++kk)
      boff[fc][kk] = rb * 64 + (((kk * 4 + g) ^ (rb & 7)) << 3);
  }

  float4v acc[4][2];
#pragma unroll
  for (int fr = 0; fr < 4; ++fr)
#pragma unroll
    for (int fc = 0; fc < 2; ++fc) acc[fr][fc] = (float4v){0.f, 0.f, 0.f, 0.f};

  // prologue: stage k-tile 0
  {
    short8 a0 = *(const short8*)agp0;
    short8 a1 = *(const short8*)agp1;
    short8 b0 = *(const short8*)bgp0;
    short8 b1 = *(const short8*)bgp1;
    *(short8*)(&als[0][0] + ld0) = a0;
    *(short8*)(&als[0][0] + ld1) = a1;
    *(short8*)(&bls[0][0] + ld0) = b0;
    *(short8*)(&bls[0][0] + ld1) = b1;
  }
  __syncthreads();

#pragma unroll 2
  for (int tt = 0; tt < 16; ++tt) {
    const int cur = tt & 1, nxt = cur ^ 1;
    short8 sA0, sA1, sB0, sB1;
    if (tt < 15) {
      const int kb = (tt + 1) * 64;
      sA0 = *(const short8*)(agp0 + kb);
      sA1 = *(const short8*)(agp1 + kb);
      sB0 = *(const short8*)(bgp0 + kb);
      sB1 = *(const short8*)(bgp1 + kb);
    }
#pragma unroll
    for (int kk = 0; kk < 2; ++kk) {
      short8 bf0 = *(const short8*)(&bls[cur][0] + boff[0][kk]);
      short8 bf1 = *(const short8*)(&bls[cur][0] + boff[1][kk]);
#pragma unroll
      for (int fr = 0; fr < 4; ++fr) {
        short8 af = *(const short8*)(&als[cur][0] + aoff[fr][kk]);
        acc[fr][0] = __builtin_amdgcn_mfma_f32_16x16x32_bf16(af, bf0, acc[fr][0], 0, 0, 0);
        acc[fr][1] = __builtin_amdgcn_mfma_f32_16x16x32_bf16(af, bf1, acc[fr][1], 0, 0, 0);
      }
    }
    if (tt < 15) {
      *(short8*)(&als[nxt][0] + ld0) = sA0;
      *(short8*)(&als[nxt][0] + ld1) = sA1;
      *(short8*)(&bls[nxt][0] + ld0) = sB0;
      *(short8*)(&bls[nxt][0] + ld1) = sB1;
      __syncthreads();
    }
  }

  // epilogue
#pragma unroll
  for (int fc = 0; fc < 2; ++fc) {
    const int col = c0 + wc * 32 + fc * 16 + lr;
    const float bv = bu[col];
#pragma unroll
    for (int fr = 0; fr < 4; ++fr)
#pragma unroll
      for (int i = 0; i < 4; ++i) {
        const int row = r0 + wr * 64 + fr * 16 + g * 4 + i;
        out[(size_t)row * EMBED + col] = acc[fr][fc][i] + bv;
      }
  }
}

// ---------------------------------------------------------------------------
extern "C" void kernel_launch(void* const* d_in, const int* in_sizes, int n_in,
                              void* d_out, int out_size, void* d_ws, size_t ws_size,
                              hipStream_t stream) {
  const float* values = (const float*)d_in[0];
  const float* keys   = (const float*)d_in[1];
  const float* query  = (const float*)d_in[2];
  const int*   mask   = (const int*)d_in[3];
  const float* Wv     = (const float*)d_in[4];
  const float* Wq     = (const float*)d_in[5];
  const float* Wk     = (const float*)d_in[6];
  const float* Wu     = (const float*)d_in[7];
  const float* bu     = (const float*)d_in[8];
  float* out = (float*)d_out;

  char* ws = (char*)d_ws;
  short* qp  = (short*)ws;                        // 8 MB  (4M bf16)
  short* kp  = qp + (1u << 22);                   // 8 MB
  short* vpT = kp + (1u << 22);                   // 8 MB (transposed, key-permuted V)
  short* ao  = vpT + (1u << 22);                  // 8 MB
  unsigned* mbits = (unsigned*)(ws + (32u << 20));        // 512 KB
  short* wub = (short*)(ws + (32u << 20) + (512u << 10)); // 2 MB

  k_pre<<<dim3(20480), 256, 0, stream>>>(values, keys, query, Wv, Wq, Wk, Wu,
                                         mask, qp, kp, vpT, mbits, wub);
  k_attn<<<dim3(1024), 256, 0, stream>>>(qp, kp, vpT, mbits, ao);
  k_gemm<<<dim3(32, 8), 512, 0, stream>>>(ao, wub, bu, out);
}